// Round 1
// baseline (2346.973 us; speedup 1.0000x reference)
//
#include <hip/hip_runtime.h>
#include <hip/hip_bf16.h>

// Problem constants (from reference): T=8, D=512, H=100, C=2, NEG=1
constexpr int D_ = 512;
constexpr int H_ = 100;
constexpr int C_ = 2;
constexpr int T_ = 8;

constexpr int TE  = 64;   // edges per block in main kernel
constexpr int DC  = 32;   // D-chunk staged in LDS
constexpr int DCP = 36;   // padded row (36%4==0 keeps float4 align; bank stride 16 -> 2-way, free)

// ---------------------------------------------------------------------------
// Stable counting sort by edge type (8 types). One block of 1024 threads.
// Produces sorted_e[p] = original edge index at stable-sorted position p,
// typeBase[8] (exclusive prefix of counts), typeCount[8].
// ---------------------------------------------------------------------------
__global__ __launch_bounds__(1024) void k_sort(const int* __restrict__ et, int E,
                                               int* __restrict__ sorted_e,
                                               int* __restrict__ typeBase,
                                               int* __restrict__ typeCount) {
    __shared__ int sc[1024][9];   // padded: stride 9, gcd(9,32)=1 -> conflict-free
    __shared__ int sbase[T_];
    const int tid = threadIdx.x;
    const int per = (E + 1023) >> 10;
    const int lo = tid * per;
    const int hi = min(E, lo + per);

    int c[T_];
#pragma unroll
    for (int j = 0; j < T_; ++j) c[j] = 0;
    for (int i = lo; i < hi; ++i) {
        int ty = et[i];
#pragma unroll
        for (int j = 0; j < T_; ++j) c[j] += (ty == j) ? 1 : 0;
    }
#pragma unroll
    for (int j = 0; j < T_; ++j) sc[tid][j] = c[j];
    __syncthreads();

    // Hillis-Steele inclusive scan over the 1024 threads (vectors of 8)
    for (int ofs = 1; ofs < 1024; ofs <<= 1) {
        int v[T_];
        if (tid >= ofs) {
#pragma unroll
            for (int j = 0; j < T_; ++j) v[j] = sc[tid - ofs][j];
        }
        __syncthreads();
        if (tid >= ofs) {
#pragma unroll
            for (int j = 0; j < T_; ++j) sc[tid][j] += v[j];
        }
        __syncthreads();
    }

    if (tid == 0) {
        int b = 0;
#pragma unroll
        for (int j = 0; j < T_; ++j) { sbase[j] = b; b += sc[1023][j]; }
    }
    __syncthreads();

    if (tid < T_) {
        typeBase[tid]  = sbase[tid];
        typeCount[tid] = sc[1023][tid];
    }

    int p[T_];
#pragma unroll
    for (int j = 0; j < T_; ++j) p[j] = sbase[j] + (tid ? sc[tid - 1][j] : 0);

    for (int i = lo; i < hi; ++i) {
        int ty = et[i];
        int r = 0;
#pragma unroll
        for (int j = 0; j < T_; ++j) {
            if (ty == j) { r = p[j]; p[j] = r + 1; }
        }
        sorted_e[r] = i;
    }
}

// ---------------------------------------------------------------------------
// Main fused kernel: per block = (type t, 64 sorted edges).
//   src_enc = h_src @ srcW[t] + srcB[t]
//   pos_enc = h_pos @ dstW[t] + dstB[t]
//   neg_enc = h_neg @ dstW[t] + dstB[t]
//   pos/neg_edge = relu(src + pos/neg); out layer 100->2; scatter to sorted pos.
// Also fuses the h_save copy (h[:2E] -> out+4E) into the staging loads.
// Thread map: 256 threads = 16 tx (j = jj*16+tx, jj<7) x 16 ty (k = ty*4+kk).
// ---------------------------------------------------------------------------
__global__ __launch_bounds__(256) void k_main(
    const float* __restrict__ h,
    const float* __restrict__ srcW, const float* __restrict__ srcB,
    const float* __restrict__ dstW, const float* __restrict__ dstB,
    const float* __restrict__ outW, const float* __restrict__ outB,
    const int* __restrict__ sorted_e,
    const int* __restrict__ typeBase, const int* __restrict__ typeCount,
    float* __restrict__ out, int E)
{
    const int t   = blockIdx.y;
    const int cnt = typeCount[t];
    const int i0  = blockIdx.x * TE;
    if (i0 >= cnt) return;
    const int base = typeBase[t];
    const int tid = threadIdx.x;
    const int tx  = tid & 15;
    const int ty  = tid >> 4;

    __shared__ __align__(16) union {
        float stage[3][TE][DCP];      // 27.6 KB
        float edge[2][TE][H_ + 1];    // 51.7 KB (pad 101: bank stride 5, conflict-free)
    } sh;
    __shared__ int eIdx[TE];

    if (tid < TE) {
        int p = i0 + tid;
        eIdx[tid] = sorted_e[base + (p < cnt ? p : i0)];  // clamp pads to a valid edge
    }

    int jcs[7];
#pragma unroll
    for (int jj = 0; jj < 7; ++jj) {
        int j = jj * 16 + tx;
        jcs[jj] = (j < H_) ? j : (H_ - 1);   // clamp to stay in-bounds; result unused
    }

    float accS[4][7], accP[4][7], accN[4][7];
#pragma unroll
    for (int kk = 0; kk < 4; ++kk)
#pragma unroll
        for (int jj = 0; jj < 7; ++jj) { accS[kk][jj] = 0.f; accP[kk][jj] = 0.f; accN[kk][jj] = 0.f; }

    float* outH = out + (size_t)4 * E;   // h_save region

    const float* wsBase = srcW + (size_t)t * D_ * H_;
    const float* wdBase = dstW + (size_t)t * D_ * H_;

    for (int d0 = 0; d0 < D_; d0 += DC) {
        __syncthreads();   // previous chunk's readers done
        // stage 3 x 64 rows x 32 cols, float4-wide; fuse h_save store
        for (int f = tid; f < 3 * TE * (DC / 4); f += 256) {   // 1536 float4s
            int m  = f >> 9;          // f / 512
            int r  = (f >> 3) & 63;
            int c4 = f & 7;
            int e  = eIdx[r];
            size_t off = ((size_t)(m * E + e)) * D_ + d0 + c4 * 4;
            float4 v = *(const float4*)(h + off);
            *(float4*)&sh.stage[m][r][c4 * 4] = v;
            if (m < 2 && (i0 + r) < cnt) *(float4*)(outH + off) = v;
        }
        __syncthreads();

        const float* pws = wsBase + (size_t)d0 * H_;
        const float* pwd = wdBase + (size_t)d0 * H_;
#pragma unroll 1
        for (int dd = 0; dd < DC; dd += 4) {
            float4 Av[3][4];
#pragma unroll
            for (int m = 0; m < 3; ++m)
#pragma unroll
                for (int kk = 0; kk < 4; ++kk)
                    Av[m][kk] = *(const float4*)&sh.stage[m][ty * 4 + kk][dd];

#pragma unroll
            for (int q = 0; q < 4; ++q) {
                const float* pws2 = pws + (size_t)(dd + q) * H_;
                const float* pwd2 = pwd + (size_t)(dd + q) * H_;
                float ws[7], wd[7];
#pragma unroll
                for (int jj = 0; jj < 7; ++jj) {
                    ws[jj] = pws2[jcs[jj]];
                    wd[jj] = pwd2[jcs[jj]];
                }
#pragma unroll
                for (int kk = 0; kk < 4; ++kk) {
                    float as = ((const float*)&Av[0][kk])[q];
                    float ap = ((const float*)&Av[1][kk])[q];
                    float an = ((const float*)&Av[2][kk])[q];
#pragma unroll
                    for (int jj = 0; jj < 7; ++jj) {
                        accS[kk][jj] += as * ws[jj];
                        accP[kk][jj] += ap * wd[jj];
                        accN[kk][jj] += an * wd[jj];
                    }
                }
            }
        }
    }

    __syncthreads();   // done with stage buffer; now reuse as edge buffer

    // bias + relu-combine into LDS
#pragma unroll
    for (int kk = 0; kk < 4; ++kk) {
        int k = ty * 4 + kk;
#pragma unroll
        for (int jj = 0; jj < 7; ++jj) {
            int j = jj * 16 + tx;
            if (j < H_) {
                float sb = srcB[t * H_ + j];
                float db = dstB[t * H_ + j];
                float s  = accS[kk][jj] + sb;
                float pz = accP[kk][jj] + db;
                float nz = accN[kk][jj] + db;
                sh.edge[0][k][j] = fmaxf(s + pz, 0.f);
                sh.edge[1][k][j] = fmaxf(s + nz, 0.f);
            }
        }
    }
    __syncthreads();

    // out layer: 256 threads -> (pn, c, k); dot over H=100, scatter to sorted pos
    {
        int pn = tid >> 7;
        int c  = (tid >> 6) & 1;
        int k  = tid & 63;
        if (i0 + k < cnt) {
            float acc = outB[t * C_ + c];
            const float* wo = outW + (size_t)t * H_ * C_ + c;
            const float* ev = &sh.edge[pn][k][0];
#pragma unroll 4
            for (int j = 0; j < H_; ++j) acc += ev[j] * wo[(size_t)j * C_];
            size_t pidx = (size_t)(base + i0 + k) * C_ + c;
            out[(pn ? (size_t)C_ * E : (size_t)0) + pidx] = acc;
        }
    }
}

// ---------------------------------------------------------------------------
extern "C" void kernel_launch(void* const* d_in, const int* in_sizes, int n_in,
                              void* d_out, int out_size, void* d_ws, size_t ws_size,
                              hipStream_t stream) {
    const float* h    = (const float*)d_in[0];
    const float* srcW = (const float*)d_in[1];
    const float* srcB = (const float*)d_in[2];
    const float* dstW = (const float*)d_in[3];
    const float* dstB = (const float*)d_in[4];
    const float* outW = (const float*)d_in[5];
    const float* outB = (const float*)d_in[6];
    const int*   et   = (const int*)d_in[7];
    const int E = in_sizes[7];

    float* out = (float*)d_out;
    int* ws = (int*)d_ws;
    int* typeBase  = ws;
    int* typeCount = ws + 8;
    int* sorted_e  = ws + 16;

    k_sort<<<1, 1024, 0, stream>>>(et, E, sorted_e, typeBase, typeCount);

    int nb = (E + TE - 1) / TE;
    dim3 grid(nb, T_);
    k_main<<<grid, 256, 0, stream>>>(h, srcW, srcB, dstW, dstB, outW, outB,
                                     sorted_e, typeBase, typeCount, out, E);
}